// Round 11
// baseline (292.141 us; speedup 1.0000x reference)
//
#include <hip/hip_runtime.h>
#include <hip/hip_bf16.h>
#include <stdint.h>
#include <math.h>

typedef __attribute__((ext_vector_type(8))) short short8;
typedef __attribute__((ext_vector_type(4))) float f32x4;

#define H_DIM 1024
#define T_SEQ 4096

static __device__ __forceinline__ float bf2f(unsigned short u) {
  union { unsigned int i; float f; } c;
  c.i = ((unsigned int)u) << 16;
  return c.f;
}

static __device__ __forceinline__ unsigned short f2bf(float f) {
  __hip_bfloat16 h = __float2bfloat16(f);  // RNE
  unsigned short u;
  __builtin_memcpy(&u, &h, 2);
  return u;
}

static __device__ __forceinline__ void gload16(const void* g, void* l) {
  __builtin_amdgcn_global_load_lds(
      (const __attribute__((address_space(1))) void*)g,
      (__attribute__((address_space(3))) void*)l,
      16, 0, 0);
}

#define FENCE asm volatile("" ::: "memory")
#define BAR   __builtin_amdgcn_s_barrier()
#define LGKM0 asm volatile("s_waitcnt lgkmcnt(0)" ::: "memory")

// ---------------------------------------------------------------------------
// Merged f32 -> bf16 conversion: one launch for X + Wq + Wk + Wv.
// grid.y: 0 = X (n8x chunks), 1..3 = weight matrices (n8w chunks each).
// Saves one serialized kernel launch + inter-launch gap (r10 accounting:
// ~85-90 us of total is non-kernel time; launch gaps are the controllable part).
// ---------------------------------------------------------------------------
__global__ __launch_bounds__(256) void cvt_all_kernel(
    const float* __restrict__ X,  __hip_bfloat16* __restrict__ Xb,  int n8x,
    const float* __restrict__ w0, __hip_bfloat16* __restrict__ o0,
    const float* __restrict__ w1, __hip_bfloat16* __restrict__ o1,
    const float* __restrict__ w2, __hip_bfloat16* __restrict__ o2, int n8w)
{
  const float* in;
  __hip_bfloat16* out;
  int n8;
  if (blockIdx.y == 0)      { in = X;  out = Xb; n8 = n8x; }
  else if (blockIdx.y == 1) { in = w0; out = o0; n8 = n8w; }
  else if (blockIdx.y == 2) { in = w1; out = o1; n8 = n8w; }
  else                      { in = w2; out = o2; n8 = n8w; }

  int i = blockIdx.x * blockDim.x + threadIdx.x;
  const int stride = gridDim.x * blockDim.x;
  for (; i < n8; i += stride) {
    const float4* p = (const float4*)in + (size_t)i * 2;
    float4 a = p[0], b = p[1];
    short8 o;
    o[0] = (short)f2bf(a.x); o[1] = (short)f2bf(a.y);
    o[2] = (short)f2bf(a.z); o[3] = (short)f2bf(a.w);
    o[4] = (short)f2bf(b.x); o[5] = (short)f2bf(b.y);
    o[6] = (short)f2bf(b.z); o[7] = (short)f2bf(b.w);
    ((short8*)out)[i] = o;
  }
}

// ---------------------------------------------------------------------------
// 8-phase 256x256 fused QKV GEMM — r8 EXACT (110 us, MfmaUtil 39.6%, 0 bank
// conflicts). r9/r10 A/B: removing the per-phase LGKM0+sched_barrier(0)
// REGRESSED to 122 us / 34.5% — the explicit drain+pin IS the better schedule
// on this structure. Keep it. (Theory-first ledger: r9 prediction falsified.)
// ---------------------------------------------------------------------------
#define GNT 16          // K tiles = 1024/64

static __device__ __forceinline__ void stage_half(
    const __hip_bfloat16* __restrict__ G, int grow0, int k0, char* dstHalf,
    int tid)
{
  const int w = tid >> 6, l = tid & 63;
  #pragma unroll
  for (int r = 0; r < 2; ++r) {
    const int D = (r * 8 + w) * 1024 + l * 16;     // linear LDS byte in half
    const int L = D ^ (((D >> 7) & 7) << 4);       // inverse-swizzled source
    const int row = L >> 7;                        // 0..127
    const int cb  = L & 127;                       // byte within 128B row
    const char* src = (const char*)G + (size_t)(grow0 + row) * (H_DIM * 2)
                      + k0 * 2 + cb;
    gload16(src, dstHalf + D);
  }
}

static __device__ __forceinline__ short8 lds_frag(const char* half, int row,
                                                  int ksub, int kq)
{
  int a = row * 128 + ksub * 64 + kq * 16;
  a ^= ((row & 7) << 4);   // same involution ((a>>7)&7 == row&7)
  return *(const short8*)(half + a);
}

__global__ __launch_bounds__(512, 1) void qkv_gemm8_kernel(
    const __hip_bfloat16* __restrict__ X,
    const __hip_bfloat16* __restrict__ Wq,
    const __hip_bfloat16* __restrict__ Wk,
    const __hip_bfloat16* __restrict__ Wv,
    const float* __restrict__ bq,
    const float* __restrict__ bk,
    const float* __restrict__ bv,
    __hip_bfloat16* __restrict__ Qo,
    __hip_bfloat16* __restrict__ Ko,
    __hip_bfloat16* __restrict__ Vo,
    int M)
{
  __shared__ char lds[131072];   // 2 bufs x (A 32KB + B 32KB)

  const int m0 = blockIdx.x * 256;
  const int ytile = blockIdx.y;          // 0..11
  const int which = ytile >> 2;          // 0:Q 1:K 2:V
  const int nb = (ytile & 3) * 256;      // col base within selected W

  const __hip_bfloat16* Wsel = (which == 0) ? Wq : ((which == 1) ? Wk : Wv);
  const float* Bsel          = (which == 0) ? bq : ((which == 1) ? bk : bv);
  __hip_bfloat16* Osel       = (which == 0) ? Qo : ((which == 1) ? Ko : Vo);

  const int tid  = threadIdx.x;
  const int lane = tid & 63;
  const int wid  = tid >> 6;       // 0..7
  const int wr   = wid >> 2;       // 0..1  (M dim, 128 rows each)
  const int wc   = wid & 3;        // 0..3  (N dim, 64 cols each)
  const int lrow = lane & 15;
  const int kq   = lane >> 4;

  // LDS regions: buf b in [b*65536, +65536): A halves at 0,16K; B at 32K,48K.
  #define AHALF(b, h) (lds + (b) * 65536 + (h) * 16384)
  #define BHALF(b, h) (lds + (b) * 65536 + 32768 + (h) * 16384)

  f32x4 acc[8][4];
  #pragma unroll
  for (int i = 0; i < 8; ++i)
    #pragma unroll
    for (int j = 0; j < 4; ++j)
      acc[i][j] = (f32x4){0.f, 0.f, 0.f, 0.f};

  // ---- Prologue: stage tile0 fully + tile1's B halves; vmcnt(4); barrier.
  stage_half(Wsel, nb +   0, 0,  BHALF(0, 0), tid);
  stage_half(Wsel, nb + 128, 0,  BHALF(0, 1), tid);
  stage_half(X,    m0 +   0, 0,  AHALF(0, 0), tid);
  stage_half(X,    m0 + 128, 0,  AHALF(0, 1), tid);
  stage_half(Wsel, nb +   0, 64, BHALF(1, 0), tid);
  stage_half(Wsel, nb + 128, 64, BHALF(1, 1), tid);
  asm volatile("s_waitcnt vmcnt(4)" ::: "memory");
  BAR;

  short8 aF[4][2];
  short8 bF[4][2];

  for (int t = 0; t < GNT; ++t) {
    const int cur = t & 1, nxt = cur ^ 1;
    const char* myA = AHALF(cur, wr);
    const char* myB = BHALF(cur, wc >> 1);
    const int rB0 = (wc & 1) * 64;

    // ---------------- phase 0: read A[m0-3], B[n0-1]; stage A0[t+1]
    #pragma unroll
    for (int mi = 0; mi < 4; ++mi)
      #pragma unroll
      for (int ks = 0; ks < 2; ++ks)
        aF[mi][ks] = lds_frag(myA, mi * 16 + lrow, ks, kq);
    #pragma unroll
    for (int ni = 0; ni < 2; ++ni)
      #pragma unroll
      for (int ks = 0; ks < 2; ++ks)
        bF[ni][ks] = lds_frag(myB, rB0 + ni * 16 + lrow, ks, kq);
    if (t + 1 < GNT) stage_half(X, m0 + 0, (t + 1) * 64, AHALF(nxt, 0), tid);
    FENCE; BAR; LGKM0; __builtin_amdgcn_sched_barrier(0);
    __builtin_amdgcn_s_setprio(1);
    #pragma unroll
    for (int mi = 0; mi < 4; ++mi)
      #pragma unroll
      for (int ni = 0; ni < 2; ++ni)
        #pragma unroll
        for (int ks = 0; ks < 2; ++ks)
          acc[mi][ni] = __builtin_amdgcn_mfma_f32_16x16x32_bf16(
              aF[mi][ks], bF[ni][ks], acc[mi][ni], 0, 0, 0);
    __builtin_amdgcn_s_setprio(0);
    FENCE; BAR;

    // ---------------- phase 1: read B[n2-3]; stage A1[t+1]
    #pragma unroll
    for (int ni = 2; ni < 4; ++ni)
      #pragma unroll
      for (int ks = 0; ks < 2; ++ks)
        bF[ni][ks] = lds_frag(myB, rB0 + ni * 16 + lrow, ks, kq);
    if (t + 1 < GNT) stage_half(X, m0 + 128, (t + 1) * 64, AHALF(nxt, 1), tid);
    FENCE; BAR; LGKM0; __builtin_amdgcn_sched_barrier(0);
    __builtin_amdgcn_s_setprio(1);
    #pragma unroll
    for (int mi = 0; mi < 4; ++mi)
      #pragma unroll
      for (int ni = 2; ni < 4; ++ni)
        #pragma unroll
        for (int ks = 0; ks < 2; ++ks)
          acc[mi][ni] = __builtin_amdgcn_mfma_f32_16x16x32_bf16(
              aF[mi][ks], bF[ni][ks], acc[mi][ni], 0, 0, 0);
    __builtin_amdgcn_s_setprio(0);
    FENCE; BAR;

    // ---------------- phase 2: read A[m4-7]; stage B0[t+2]
    #pragma unroll
    for (int mi = 0; mi < 4; ++mi)
      #pragma unroll
      for (int ks = 0; ks < 2; ++ks)
        aF[mi][ks] = lds_frag(myA, (mi + 4) * 16 + lrow, ks, kq);
    if (t + 2 < GNT) stage_half(Wsel, nb + 0, (t + 2) * 64, BHALF(cur, 0), tid);
    FENCE; BAR; LGKM0; __builtin_amdgcn_sched_barrier(0);
    __builtin_amdgcn_s_setprio(1);
    #pragma unroll
    for (int mi = 0; mi < 4; ++mi)
      #pragma unroll
      for (int ni = 0; ni < 2; ++ni)
        #pragma unroll
        for (int ks = 0; ks < 2; ++ks)
          acc[mi + 4][ni] = __builtin_amdgcn_mfma_f32_16x16x32_bf16(
              aF[mi][ks], bF[ni][ks], acc[mi + 4][ni], 0, 0, 0);
    __builtin_amdgcn_s_setprio(0);
    FENCE; BAR;

    // ---------------- phase 3: stage B1[t+2]; MFMA from regs; tile-end vmcnt
    if (t + 2 < GNT) stage_half(Wsel, nb + 128, (t + 2) * 64, BHALF(cur, 1), tid);
    FENCE;
    __builtin_amdgcn_s_setprio(1);
    #pragma unroll
    for (int mi = 0; mi < 4; ++mi)
      #pragma unroll
      for (int ni = 2; ni < 4; ++ni)
        #pragma unroll
        for (int ks = 0; ks < 2; ++ks)
          acc[mi + 4][ni] = __builtin_amdgcn_mfma_f32_16x16x32_bf16(
              aF[mi][ks], bF[ni][ks], acc[mi + 4][ni], 0, 0, 0);
    __builtin_amdgcn_s_setprio(0);
    // End-of-tile: ensure tile t+1's 4 halves have landed before anyone reads.
    if (t + 2 < GNT) { asm volatile("s_waitcnt vmcnt(4)" ::: "memory"); }
    else             { asm volatile("s_waitcnt vmcnt(0)" ::: "memory"); }
    FENCE; BAR;
  }

  // ---- Epilogue: bias + bf16 store. C/D: col=lane&15, row=(lane>>4)*4+reg.
  #pragma unroll
  for (int ni = 0; ni < 4; ++ni) {
    const int col = nb + wc * 64 + ni * 16 + lrow;
    const float bias = Bsel[col];
    #pragma unroll
    for (int mi = 0; mi < 8; ++mi) {
      const int rowbase = m0 + wr * 128 + mi * 16 + kq * 4;
      #pragma unroll
      for (int r = 0; r < 4; ++r) {
        float v = acc[mi][ni][r] + bias;
        Osel[(size_t)(rowbase + r) * H_DIM + col] = __float2bfloat16(v);
      }
    }
  }
  #undef AHALF
  #undef BHALF
}

// ---------------------------------------------------------------------------
// Windowed causal attention (r4-verified, ~64 us). One wave per row.
// ---------------------------------------------------------------------------
__global__ __launch_bounds__(256) void local_attn_kernel(
    const __hip_bfloat16* __restrict__ Q,
    const __hip_bfloat16* __restrict__ Km,
    const __hip_bfloat16* __restrict__ V,
    const int* __restrict__ winp,
    float* __restrict__ Out,
    int M)
{
  const int row = (int)((blockIdx.x * blockDim.x + threadIdx.x) >> 6);
  if (row >= M) return;
  const int lane = threadIdx.x & 63;
  const int t = row & (T_SEQ - 1);
  const int Wn = *winp;  // 8 for this problem
  const float scale = 0.03125f;  // 1/sqrt(1024)

  const size_t base = (size_t)row * H_DIM + (size_t)lane * 16;

  float q[16];
  {
    const short8* p = (const short8*)(Q + base);
    short8 a = p[0], b = p[1];
    #pragma unroll
    for (int j = 0; j < 8; ++j) {
      q[j]     = bf2f((unsigned short)a[j]);
      q[8 + j] = bf2f((unsigned short)b[j]);
    }
  }

  if (Wn == 8) {
    float sc[9];
    #pragma unroll
    for (int w = 0; w < 9; ++w) {
      const int dt = 8 - w;
      float s = -INFINITY;
      if (t - dt >= 0) {
        const short8* kp = (const short8*)(Km + base - (size_t)dt * H_DIM);
        short8 ka = kp[0], kb = kp[1];
        float d = 0.f;
        #pragma unroll
        for (int j = 0; j < 8; ++j) {
          d += q[j]     * bf2f((unsigned short)ka[j]);
          d += q[8 + j] * bf2f((unsigned short)kb[j]);
        }
        #pragma unroll
        for (int off = 32; off >= 1; off >>= 1) d += __shfl_xor(d, off, 64);
        s = d * scale;
      }
      sc[w] = s;
    }
    float m = sc[0];
    #pragma unroll
    for (int w = 1; w < 9; ++w) m = fmaxf(m, sc[w]);
    float l = 0.f;
    #pragma unroll
    for (int w = 0; w < 9; ++w) { sc[w] = __expf(sc[w] - m); l += sc[w]; }
    const float inv = 1.f / l;

    float o[16];
    #pragma unroll
    for (int j = 0; j < 16; ++j) o[j] = 0.f;
    #pragma unroll
    for (int w = 0; w < 9; ++w) {
      const int dt = 8 - w;
      if (t - dt >= 0) {
        const short8* vp = (const short8*)(V + base - (size_t)dt * H_DIM);
        short8 va = vp[0], vb = vp[1];
        const float aw = sc[w] * inv;
        #pragma unroll
        for (int j = 0; j < 8; ++j) {
          o[j]     += aw * bf2f((unsigned short)va[j]);
          o[8 + j] += aw * bf2f((unsigned short)vb[j]);
        }
      }
    }

    float4* op = (float4*)(Out + base);
    op[0] = (float4){o[0],  o[1],  o[2],  o[3]};
    op[1] = (float4){o[4],  o[5],  o[6],  o[7]};
    op[2] = (float4){o[8],  o[9],  o[10], o[11]};
    op[3] = (float4){o[12], o[13], o[14], o[15]};
  } else {
    float m = -INFINITY, l = 0.f;
    float o[16];
    #pragma unroll
    for (int j = 0; j < 16; ++j) o[j] = 0.f;
    for (int w = 0; w <= Wn; ++w) {
      const int dt = Wn - w;
      if (t - dt < 0) continue;
      const short8* kp = (const short8*)(Km + base - (size_t)dt * H_DIM);
      short8 ka = kp[0], kb = kp[1];
      float d = 0.f;
      #pragma unroll
      for (int j = 0; j < 8; ++j) {
        d += q[j]     * bf2f((unsigned short)ka[j]);
        d += q[8 + j] * bf2f((unsigned short)kb[j]);
      }
      #pragma unroll
      for (int off = 32; off >= 1; off >>= 1) d += __shfl_xor(d, off, 64);
      const float s = d * scale;
      const float mn = fmaxf(m, s);
      const float corr = (m == -INFINITY) ? 0.f : __expf(m - mn);
      const float p = __expf(s - mn);
      l = l * corr + p;
      const short8* vp = (const short8*)(V + base - (size_t)dt * H_DIM);
      short8 va = vp[0], vb = vp[1];
      #pragma unroll
      for (int j = 0; j < 8; ++j) {
        o[j]     = o[j]     * corr + p * bf2f((unsigned short)va[j]);
        o[8 + j] = o[8 + j] * corr + p * bf2f((unsigned short)vb[j]);
      }
      m = mn;
    }
    const float inv = 1.f / l;
    float4* op = (float4*)(Out + base);
    op[0] = (float4){o[0]  * inv, o[1]  * inv, o[2]  * inv, o[3]  * inv};
    op[1] = (float4){o[4]  * inv, o[5]  * inv, o[6]  * inv, o[7]  * inv};
    op[2] = (float4){o[8]  * inv, o[9]  * inv, o[10] * inv, o[11] * inv};
    op[3] = (float4){o[12] * inv, o[13] * inv, o[14] * inv, o[15] * inv};
  }
}

extern "C" void kernel_launch(void* const* d_in, const int* in_sizes, int n_in,
                              void* d_out, int out_size, void* d_ws, size_t ws_size,
                              hipStream_t stream) {
  const float* X  = (const float*)d_in[0];
  const float* Wq = (const float*)d_in[1];
  const float* bq = (const float*)d_in[2];
  const float* Wk = (const float*)d_in[3];
  const float* bk = (const float*)d_in[4];
  const float* Wv = (const float*)d_in[5];
  const float* bv = (const float*)d_in[6];
  const int* winp = (const int*)d_in[7];

  const int M = in_sizes[0] / H_DIM;  // B*T = 16384
  const size_t MH = (size_t)M * H_DIM;
  const size_t HH = (size_t)H_DIM * H_DIM;

  // Workspace (bf16): Xb | Wqb | Wkb | Wvb | Qb | Kb | Vb  (~134 MiB)
  __hip_bfloat16* Xb  = (__hip_bfloat16*)d_ws;
  __hip_bfloat16* Wqb = Xb  + MH;
  __hip_bfloat16* Wkb = Wqb + HH;
  __hip_bfloat16* Wvb = Wkb + HH;
  __hip_bfloat16* Qb  = Wvb + HH;
  __hip_bfloat16* Kb  = Qb  + MH;
  __hip_bfloat16* Vb  = Kb  + MH;
  float* Out = (float*)d_out;

  // 1) f32 -> bf16 conversions (single merged launch).
  cvt_all_kernel<<<dim3(1024, 4), 256, 0, stream>>>(
      X, Xb, (int)(MH / 8), Wq, Wqb, Wk, Wkb, Wv, Wvb, (int)(HH / 8));

  // 2) Fused QKV GEMM — 8-phase 256x256 (r8 exact).
  dim3 g1(M / 256, 12);  // 64 x 12 = 768 blocks, 512 threads
  qkv_gemm8_kernel<<<g1, 512, 0, stream>>>(Xb, Wqb, Wkb, Wvb, bq, bk, bv,
                                           Qb, Kb, Vb, M);

  // 3) Windowed attention (r4 per-row version, f32 out).
  const int blocks = M / 4;  // 1 wave per row, 4 waves per 256-thread block
  local_attn_kernel<<<blocks, 256, 0, stream>>>(Qb, Kb, Vb, winp, Out, M);
}